// Round 2
// baseline (954.483 us; speedup 1.0000x reference)
//
#include <hip/hip_runtime.h>

#define EPS_C 0.01f
#define NU    128
#define DIN   64
#define COUT  10

typedef float    f32x4 __attribute__((ext_vector_type(4)));
typedef _Float16 f16x4 __attribute__((ext_vector_type(4)));
typedef _Float16 f16x8 __attribute__((ext_vector_type(8)));

#define MFMA32(A, B, C) __builtin_amdgcn_mfma_f32_16x16x32_f16((A), (B), (C), 0, 0, 0)
// LDS-only barrier: vmcnt stays in flight across the per-step sync.
#define BAR() asm volatile("s_waitcnt lgkmcnt(0)\n\ts_barrier" ::: "memory")

// Transposed recurrence h^T(t+1) = h^T + eps*(A^T h^T + tanh(W^T h^T + z^T)).
// TWO independent 16-row batch groups per block (32 rows, grid=16): the step
// was latency-bound (~1040 cyc/step vs ~350 cyc of issue work; r0->r1 big
// structural change moved nothing). Interleaving G0/G1 in one instruction
// stream hides ds_read latency, MFMA dep chains and the tanh chain of one
// group under the other group's work; one barrier serves both groups.
// 4 waves (256 thr), wave w owns units [32w, 32w+32) = m-tiles 2w, 2w+1.
// Weight fragments (AT/WT/EF/ebv) are shared across groups — no extra VGPR.
// mfma_f32_16x16x32_f16 layouts (HW-verified in prior rounds):
//   A-op: A[m = lane&15][k = quad*8 + j]
//   B-op: B[k = quad*8 + j][n = lane&15]
//   D   : D[row = quad*4 + reg][col = lane&15]
// h exchange per group: unit u = 32w+16mt+4q+r, batch lid ->
//   hbuf[gr][np][kt=w][(2mt+(q>>1))*16+lid][4(q&1)+r]  (f16x4 write, 2-way
//   bank aliasing = free; reads are linear ds_read_b128, conflict-free)
__global__ __launch_bounds__(256, 1)
void rnn_core(const float* __restrict__ x,
              const float* __restrict__ E_w, const float* __restrict__ E_b,
              const float* __restrict__ B_p, const float* __restrict__ C_p,
              const float* __restrict__ D_w, const float* __restrict__ D_b,
              float* __restrict__ out, int T)
{
    const int tid  = threadIdx.x;
    const int lane = tid & 63;
    const int w    = tid >> 6;     // wave 0..3
    const int lid  = lane & 15;
    const int q    = lane >> 4;
    const int g    = blockIdx.x;   // 32-row super-group

    // xs[gr][buf]: 8 steps of x in B-frag layout [t8][kt2][lane64][8 halves]
    __shared__ __attribute__((aligned(16))) _Float16 xs[2][2][8192];      // 64 KB
    __shared__ __attribute__((aligned(16))) _Float16 hbuf[2][2][4][64][8];// 16 KB
    __shared__ float hfin[32][NU + 4];                                    // 16.9 KB

    // ---- one-time weight fragments (wave w: m = 32w + 16mt + lid) ----
    f16x8 AT[2][4], WT[2][4], EF[2][2];
    f32x4 ebv[2];
    #pragma unroll
    for (int mt = 0; mt < 2; ++mt) {
        const int m = w * 32 + mt * 16 + lid;
        #pragma unroll
        for (int kt = 0; kt < 4; ++kt) {
            f16x8 fa, fw;
            #pragma unroll
            for (int j = 0; j < 8; ++j) {
                const int k  = kt * 32 + q * 8 + j;
                const float dg = (k == m) ? 0.01f : 0.0f;
                fa[j] = (_Float16)(B_p[k * NU + m] - 0.6f * B_p[m * NU + k] - dg);
                fw[j] = (_Float16)(C_p[k * NU + m] - 0.6f * C_p[m * NU + k] - dg);
            }
            AT[mt][kt] = fa;  WT[mt][kt] = fw;
        }
        #pragma unroll
        for (int kt = 0; kt < 2; ++kt) {
            f16x8 fe;
            #pragma unroll
            for (int j = 0; j < 8; ++j)
                fe[j] = (_Float16)E_w[m * DIN + kt * 32 + q * 8 + j];
            EF[mt][kt] = fe;
        }
        #pragma unroll
        for (int r = 0; r < 4; ++r)
            ebv[mt][r] = E_b[w * 32 + mt * 16 + q * 4 + r];
    }

    // ---- x staging mapping (256 loader threads, 1 float4/step/group) ----
    const int bb = tid & 15;        // batch row within group
    const int s2 = tid >> 4;        // d-quad 0..15
    const float* xrow0 = x + ((size_t)(g * 32 + bb) * T) * DIN + s2 * 4;
    const float* xrow1 = xrow0 + (size_t)16 * T * DIN;
    const int wb2 = (((s2 >> 3) * 64) + (((s2 >> 1) & 3) * 16) + bb) * 16 + (s2 & 1) * 8;

    float4 xg[8];   // one chunk = 8 steps; G0/G1 lifetimes staggered

#define STAGE_WRITE(GR, BUF)                                                  \
    {                                                                         \
        char* base_ = (char*)xs + (GR) * 32768 + (BUF) * 16384;               \
        _Pragma("unroll")                                                     \
        for (int i2 = 0; i2 < 8; ++i2) {                                      \
            float4 v_ = xg[i2];                                               \
            f16x4 h4_;                                                        \
            h4_[0] = (_Float16)v_.x; h4_[1] = (_Float16)v_.y;                 \
            h4_[2] = (_Float16)v_.z; h4_[3] = (_Float16)v_.w;                 \
            *(f16x4*)(base_ + i2 * 2048 + wb2) = h4_;                         \
        }                                                                     \
    }

    // ---- init: zero both groups' h buffers; stage chunk 0 for G0, G1 ----
    #pragma unroll
    for (int k2 = 0; k2 < 4; ++k2)
        ((float4*)hbuf)[k2 * 256 + tid] = (float4){0.f, 0.f, 0.f, 0.f};
    #pragma unroll
    for (int i = 0; i < 8; ++i)
        xg[i] = *(const float4*)(xrow0 + (size_t)i * DIN);
    STAGE_WRITE(0, 0)
    #pragma unroll
    for (int i = 0; i < 8; ++i)
        xg[i] = *(const float4*)(xrow1 + (size_t)i * DIN);
    STAGE_WRITE(1, 0)
    __syncthreads();

    // precomputed LDS byte bases
    char* xsb = (char*)xs + lane * 16;       // +gr*32768 +buf*16384 +it*2048 +kt*1024
    char* hrb = (char*)hbuf + lane * 16;     // +gr*8192 +p*4096 +kt*1024
    char* hwb = (char*)hbuf
              + (w * 64 + (q >> 1) * 16 + lid) * 16 + (q & 1) * 8;  // +gr*8192 +np*4096 +mt*512

    // ---- state init: h = 0, z_cur = z(0) per group ----
    f32x4 hf[2][2] = {{{0.f,0.f,0.f,0.f},{0.f,0.f,0.f,0.f}},
                      {{0.f,0.f,0.f,0.f},{0.f,0.f,0.f,0.f}}};
    f32x4 zc[2][2];
    #pragma unroll
    for (int gr = 0; gr < 2; ++gr) {
        f16x8 xa = *(const f16x8*)(xsb + gr * 32768);
        f16x8 xb = *(const f16x8*)(xsb + gr * 32768 + 1024);
        #pragma unroll
        for (int mt = 0; mt < 2; ++mt) {
            f32x4 z = ebv[mt];
            z = MFMA32(EF[mt][0], xa, z);
            z = MFMA32(EF[mt][1], xb, z);
            zc[gr][mt] = z;
        }
    }

    const int nch = T >> 3;   // 128 chunks of 8 steps
    for (int c = 0; c < nch; ++c) {
        #pragma unroll
        for (int i = 0; i < 8; ++i) {
            const int t  = c * 8 + i;
            const int p  = i & 1;
            const int np = p ^ 1;

            // G0 next-chunk loads issue at i==0 (staged at i==3)
            if (i == 0 && c + 1 < nch) {
                const float* xr = xrow0 + (size_t)(c + 1) * 8 * DIN;
                #pragma unroll
                for (int k = 0; k < 8; ++k)
                    xg[k] = *(const float4*)(xr + (size_t)k * DIN);
            }

            // h B-frags, both groups (8x ds_read_b128, issue early)
            f16x8 hB[2][4];
            #pragma unroll
            for (int gr = 0; gr < 2; ++gr)
                #pragma unroll
                for (int kt = 0; kt < 4; ++kt)
                    hB[gr][kt] = *(const f16x8*)(hrb + gr * 8192 + p * 4096 + kt * 1024);

            // x B-frags for t+1 (z_next, off critical path)
            int tt = t + 1; if (tt >= T) tt = T - 1;
            const int xoff = ((tt >> 3) & 1) * 16384 + (tt & 7) * 2048;
            f16x8 xf[2][2];
            #pragma unroll
            for (int gr = 0; gr < 2; ++gr) {
                xf[gr][0] = *(const f16x8*)(xsb + gr * 32768 + xoff);
                xf[gr][1] = *(const f16x8*)(xsb + gr * 32768 + xoff + 1024);
            }

            // W chains FIRST (tanh critical path): 4 independent depth-4 chains
            f32x4 wa[2][2], ya[2][2], zn[2][2];
            #pragma unroll
            for (int gr = 0; gr < 2; ++gr) {
                wa[gr][0] = zc[gr][0]; wa[gr][1] = zc[gr][1];
            }
            #pragma unroll
            for (int kt = 0; kt < 4; ++kt)
                #pragma unroll
                for (int gr = 0; gr < 2; ++gr) {
                    wa[gr][0] = MFMA32(WT[0][kt], hB[gr][kt], wa[gr][0]);
                    wa[gr][1] = MFMA32(WT[1][kt], hB[gr][kt], wa[gr][1]);
                }
            // A chains + z(t+1): independent work that covers the tanh window
            #pragma unroll
            for (int gr = 0; gr < 2; ++gr) {
                ya[gr][0] = (f32x4){0.f,0.f,0.f,0.f};
                ya[gr][1] = (f32x4){0.f,0.f,0.f,0.f};
            }
            #pragma unroll
            for (int kt = 0; kt < 4; ++kt)
                #pragma unroll
                for (int gr = 0; gr < 2; ++gr) {
                    ya[gr][0] = MFMA32(AT[0][kt], hB[gr][kt], ya[gr][0]);
                    ya[gr][1] = MFMA32(AT[1][kt], hB[gr][kt], ya[gr][1]);
                }
            #pragma unroll
            for (int gr = 0; gr < 2; ++gr) {
                zn[gr][0] = ebv[0]; zn[gr][1] = ebv[1];
                zn[gr][0] = MFMA32(EF[0][0], xf[gr][0], zn[gr][0]);
                zn[gr][1] = MFMA32(EF[1][0], xf[gr][0], zn[gr][1]);
                zn[gr][0] = MFMA32(EF[0][1], xf[gr][1], zn[gr][0]);
                zn[gr][1] = MFMA32(EF[1][1], xf[gr][1], zn[gr][1]);
            }

            // ---- epilogues: h += eps*(ya + tanh(wa)); D->B shuffled write ----
            #pragma unroll
            for (int gr = 0; gr < 2; ++gr) {
                #pragma unroll
                for (int mt = 0; mt < 2; ++mt) {
                    f16x4 nh;
                    #pragma unroll
                    for (int r = 0; r < 4; ++r) {
                        // tanh(x) = 1 - 2/(exp2(2x*log2e)+1)
                        const float e2 = __builtin_amdgcn_exp2f(wa[gr][mt][r] * 2.8853900817779268f);
                        const float th = 1.0f - 2.0f * __builtin_amdgcn_rcpf(e2 + 1.0f);
                        const float hv = hf[gr][mt][r] + EPS_C * (ya[gr][mt][r] + th);
                        hf[gr][mt][r] = hv;
                        nh[r] = (_Float16)hv;
                    }
                    *(f16x4*)(hwb + gr * 8192 + np * 4096 + mt * 512) = nh;
                }
                zc[gr][0] = zn[gr][0]; zc[gr][1] = zn[gr][1];
            }

            // staggered staging: G0 stage + G1 load at i==3, G1 stage at i==6
            // (both buffers complete before i==7 reads t+1 from next buf)
            if (i == 3 && c + 1 < nch) {
                STAGE_WRITE(0, (c + 1) & 1)
                const float* xr = xrow1 + (size_t)(c + 1) * 8 * DIN;
                #pragma unroll
                for (int k = 0; k < 8; ++k)
                    xg[k] = *(const float4*)(xr + (size_t)k * DIN);
            }
            if (i == 6 && c + 1 < nch) STAGE_WRITE(1, (c + 1) & 1)
            BAR();   // lgkmcnt(0) + s_barrier; vmcnt stays in flight
        }
    }

    // ---- final: stash h, small output GEMM (32 rows x 10 cols) ----
    #pragma unroll
    for (int gr = 0; gr < 2; ++gr)
        #pragma unroll
        for (int mt = 0; mt < 2; ++mt)
            #pragma unroll
            for (int r = 0; r < 4; ++r)
                hfin[gr * 16 + lid][w * 32 + mt * 16 + q * 4 + r] = hf[gr][mt][r];
    __syncthreads();

    for (int idx = tid; idx < 32 * COUT; idx += 256) {
        const int r  = idx / COUT;
        const int cc = idx - r * COUT;
        float acc = D_b[cc];
        #pragma unroll 8
        for (int u = 0; u < NU; ++u)
            acc = fmaf(hfin[r][u], D_w[cc * NU + u], acc);
        out[((size_t)g * 32 + r) * COUT + cc] = acc;
    }
}

extern "C" void kernel_launch(void* const* d_in, const int* in_sizes, int n_in,
                              void* d_out, int out_size, void* d_ws, size_t ws_size,
                              hipStream_t stream)
{
    const float* x   = (const float*)d_in[0];
    const float* E_w = (const float*)d_in[1];
    const float* E_b = (const float*)d_in[2];
    const float* B_p = (const float*)d_in[3];
    const float* C_p = (const float*)d_in[4];
    const float* D_w = (const float*)d_in[5];
    const float* D_b = (const float*)d_in[6];
    float* out = (float*)d_out;

    const int B  = out_size / COUT;            // 512
    const int T  = in_sizes[0] / (B * DIN);    // 1024
    const int NB = B / 32;                     // 16 blocks (2 groups each)

    rnn_core<<<NB, 256, 0, stream>>>(x, E_w, E_b, B_p, C_p, D_w, D_b, out, T);
}

// Round 3
// 677.588 us; speedup vs baseline: 1.4086x; 1.4086x over previous
//
#include <hip/hip_runtime.h>

#define EPS_C 0.01f
#define NU    128
#define DIN   64
#define COUT  10

typedef float    f32x4 __attribute__((ext_vector_type(4)));
typedef _Float16 f16x4 __attribute__((ext_vector_type(4)));
typedef _Float16 f16x8 __attribute__((ext_vector_type(8)));

#define MFMA32(A, B, C) __builtin_amdgcn_mfma_f32_16x16x32_f16((A), (B), (C), 0, 0, 0)
// LDS-only barrier: vmcnt stays in flight across the per-step sync.
#define BAR() asm volatile("s_waitcnt lgkmcnt(0)\n\ts_barrier" ::: "memory")

// ---------------------------------------------------------------------------
// Phase 1: z(t,b,u) = E_w x(t,b) + E_b precomputed for ALL steps on ALL CUs.
// Rationale (r2 post-mortem): the recurrent step is throughput-bound on the
// per-SIMD instruction stream (time ~ linear in per-wave work, r0/r1/r2).
// z is 20% of the step's MFMA pipe + all of the x-staging VALU/LDS work and
// has no dependence on h -> hoist it out of the serial loop entirely.
// Output layout = MFMA C-fragment order so the recurrent kernel loads it with
// one coalesced dwordx4 per (wave, m-tile):
//   zf[((g*T + t)*32 + u4)*64 + lid*4 + r] , u4 = u>>2, holds z[u][b=lid]
// ---------------------------------------------------------------------------
__global__ __launch_bounds__(256, 1)
void z_pre(const float* __restrict__ x, const float* __restrict__ E_w,
           const float* __restrict__ E_b, float* __restrict__ zf, int T)
{
    const int tid  = threadIdx.x;
    const int lane = tid & 63;
    const int w    = tid >> 6;
    const int lid  = lane & 15;
    const int q    = lane >> 4;
    const int tc   = blockIdx.x;   // 8-step chunk
    const int g    = blockIdx.y;   // 16-row batch group

    __shared__ __attribute__((aligned(16))) _Float16 xs[8192];

    // E fragments (wave w: m = 32w + 16mt + lid), bias in D-layout
    f16x8 EF[2][2];
    f32x4 ebv[2];
    #pragma unroll
    for (int mt = 0; mt < 2; ++mt) {
        const int m = w * 32 + mt * 16 + lid;
        #pragma unroll
        for (int kt = 0; kt < 2; ++kt) {
            f16x8 fe;
            #pragma unroll
            for (int j = 0; j < 8; ++j)
                fe[j] = (_Float16)E_w[m * DIN + kt * 32 + q * 8 + j];
            EF[mt][kt] = fe;
        }
        #pragma unroll
        for (int r = 0; r < 4; ++r)
            ebv[mt][r] = E_b[w * 32 + mt * 16 + q * 4 + r];
    }

    // stage x (16 rows x 8 steps x 64 d) into B-frag layout (verified r0/r1)
    const int bb = tid & 15;
    const int s2 = tid >> 4;
    const float* xrow = x + ((size_t)(g * 16 + bb) * T + (size_t)tc * 8) * DIN + s2 * 4;
    const int wb2 = (((s2 >> 3) * 64) + (((s2 >> 1) & 3) * 16) + bb) * 16 + (s2 & 1) * 8;
    #pragma unroll
    for (int i = 0; i < 8; ++i) {
        float4 v = *(const float4*)(xrow + (size_t)i * DIN);
        f16x4 h4;
        h4[0] = (_Float16)v.x; h4[1] = (_Float16)v.y;
        h4[2] = (_Float16)v.z; h4[3] = (_Float16)v.w;
        *(f16x4*)((char*)xs + i * 2048 + wb2) = h4;
    }
    __syncthreads();

    const char* xsb = (const char*)xs + lane * 16;
    float* zd = zf + ((size_t)g * T + (size_t)tc * 8) * 2048 + w * 512 + q * 64 + lid * 4;
    #pragma unroll
    for (int i = 0; i < 8; ++i) {
        f16x8 x0 = *(const f16x8*)(xsb + i * 2048);
        f16x8 x1 = *(const f16x8*)(xsb + i * 2048 + 1024);
        #pragma unroll
        for (int mt = 0; mt < 2; ++mt) {
            f32x4 z = ebv[mt];
            z = MFMA32(EF[mt][0], x0, z);
            z = MFMA32(EF[mt][1], x1, z);
            *(f32x4*)(zd + (size_t)i * 2048 + mt * 256) = z;  // coalesced 1KB/wave
        }
    }
}

// ---------------------------------------------------------------------------
// Phase 2: recurrence with precomputed z. r1 structure (4 waves, 32 blocks),
// minus z-MFMAs, minus all x staging. z(t) prefetched 2 steps ahead straight
// into the W-chain accumulator (C-input); barrier never drains vmcnt.
// Per-SIMD per-step stream: 4 ds_read_b128 + 16 MFMA + 2 dwordx4 + epilogue.
// ---------------------------------------------------------------------------
__global__ __launch_bounds__(256, 1)
void rnn_core_z(const float* __restrict__ B_p, const float* __restrict__ C_p,
                const float* __restrict__ D_w, const float* __restrict__ D_b,
                const float* __restrict__ zf, float* __restrict__ out, int T)
{
    const int tid  = threadIdx.x;
    const int lane = tid & 63;
    const int w    = tid >> 6;     // wave 0..3
    const int lid  = lane & 15;
    const int q    = lane >> 4;
    const int g    = blockIdx.x;   // batch group (16 rows)

    __shared__ __attribute__((aligned(16))) _Float16 hbuf[2][4][64][8]; // 8 KB
    __shared__ float hfin[16][NU + 4];

    // ---- one-time weight fragments (wave w: m = 32w + 16mt + lid) ----
    f16x8 AT[2][4], WT[2][4];
    #pragma unroll
    for (int mt = 0; mt < 2; ++mt) {
        const int m = w * 32 + mt * 16 + lid;
        #pragma unroll
        for (int kt = 0; kt < 4; ++kt) {
            f16x8 fa, fw;
            #pragma unroll
            for (int j = 0; j < 8; ++j) {
                const int k  = kt * 32 + q * 8 + j;
                const float dg = (k == m) ? 0.01f : 0.0f;
                fa[j] = (_Float16)(B_p[k * NU + m] - 0.6f * B_p[m * NU + k] - dg);
                fw[j] = (_Float16)(C_p[k * NU + m] - 0.6f * C_p[m * NU + k] - dg);
            }
            AT[mt][kt] = fa;  WT[mt][kt] = fw;
        }
    }

    // ---- init: zero parity-0 h buffer ----
    ((float4*)&hbuf[0][0][0][0])[tid] = (float4){0.f, 0.f, 0.f, 0.f};
    __syncthreads();

    // LDS byte bases (layout algebra verified r0/r1)
    char* hrb = (char*)hbuf + lane * 16;      // +p*4096 +kt*1024
    char* hwb = (char*)hbuf
              + (w * 64 + (q >> 1) * 16 + lid) * 16 + (q & 1) * 8;  // +np*4096 +mt*512

    // z stream base for this (wave, lane)
    const float* zbase = zf + (size_t)g * T * 2048 + w * 512 + q * 64 + lid * 4;
#define ZLD(T_, MT_) (*(const f32x4*)(zbase + (size_t)(T_) * 2048 + (MT_) * 256))

    // ---- state: h = 0; z regs 2-deep (slot = t&1) ----
    f32x4 hf[2] = {{0.f,0.f,0.f,0.f}, {0.f,0.f,0.f,0.f}};
    f32x4 zs[2][2];
    zs[0][0] = ZLD(0, 0);  zs[0][1] = ZLD(0, 1);
    zs[1][0] = ZLD(1, 0);  zs[1][1] = ZLD(1, 1);

    const int nch = T >> 3;
    for (int c = 0; c < nch; ++c) {
        #pragma unroll
        for (int i = 0; i < 8; ++i) {
            const int t  = c * 8 + i;
            const int sl = i & 1;      // z slot = t&1 (compile-time in body)
            const int p  = i & 1;
            const int np = p ^ 1;

            // h B-frags (linear ds_read_b128, conflict-free)
            f16x8 hB[4];
            #pragma unroll
            for (int kt = 0; kt < 4; ++kt)
                hB[kt] = *(const f16x8*)(hrb + p * 4096 + kt * 1024);

            // W chains first (tanh critical path), C-input = prefetched z(t)
            f32x4 wa0 = zs[sl][0], wa1 = zs[sl][1];
            #pragma unroll
            for (int kt = 0; kt < 4; ++kt) {
                wa0 = MFMA32(WT[0][kt], hB[kt], wa0);
                wa1 = MFMA32(WT[1][kt], hB[kt], wa1);
            }
            f32x4 ya0 = {0.f,0.f,0.f,0.f}, ya1 = {0.f,0.f,0.f,0.f};
            #pragma unroll
            for (int kt = 0; kt < 4; ++kt) {
                ya0 = MFMA32(AT[0][kt], hB[kt], ya0);
                ya1 = MFMA32(AT[1][kt], hB[kt], ya1);
            }

            // refill slot with z(t+2): overlaps epilogue + next step's MFMAs
            {
                int t2 = t + 2; if (t2 >= T) t2 = T - 1;
                zs[sl][0] = ZLD(t2, 0);
                zs[sl][1] = ZLD(t2, 1);
            }

            // ---- epilogue: h += eps*(ya + tanh(wa)); D->B shuffled write ----
            #pragma unroll
            for (int mt = 0; mt < 2; ++mt) {
                f32x4 wa = mt ? wa1 : wa0;
                f32x4 ya = mt ? ya1 : ya0;
                f16x4 nh;
                #pragma unroll
                for (int r = 0; r < 4; ++r) {
                    // tanh(x) = 1 - 2/(exp2(2x*log2e)+1)
                    const float e2 = __builtin_amdgcn_exp2f(wa[r] * 2.8853900817779268f);
                    const float th = 1.0f - 2.0f * __builtin_amdgcn_rcpf(e2 + 1.0f);
                    const float hv = hf[mt][r] + EPS_C * (ya[r] + th);
                    hf[mt][r] = hv;
                    nh[r] = (_Float16)hv;
                }
                *(f16x4*)(hwb + np * 4096 + mt * 512) = nh;
            }

            BAR();   // lgkmcnt(0) + s_barrier; z loads stay in flight
        }
    }

    // ---- final: stash h, small output GEMM ----
    #pragma unroll
    for (int mt = 0; mt < 2; ++mt)
        #pragma unroll
        for (int r = 0; r < 4; ++r)
            hfin[lid][w * 32 + mt * 16 + q * 4 + r] = hf[mt][r];
    __syncthreads();

    if (tid < 16 * COUT) {
        const int r  = tid / COUT;
        const int cc = tid - r * COUT;
        float acc = D_b[cc];
        #pragma unroll 8
        for (int u = 0; u < NU; ++u)
            acc = fmaf(hfin[r][u], D_w[cc * NU + u], acc);
        out[((size_t)g * 16 + r) * COUT + cc] = acc;
    }
}

// ---------------------------------------------------------------------------
// Fallback (r1 kernel, proven): used only if workspace can't hold z.
// ---------------------------------------------------------------------------
__global__ __launch_bounds__(256, 1)
void rnn_core_v1(const float* __restrict__ x,
                 const float* __restrict__ E_w, const float* __restrict__ E_b,
                 const float* __restrict__ B_p, const float* __restrict__ C_p,
                 const float* __restrict__ D_w, const float* __restrict__ D_b,
                 float* __restrict__ out, int T)
{
    const int tid  = threadIdx.x;
    const int lane = tid & 63;
    const int w    = tid >> 6;
    const int lid  = lane & 15;
    const int q    = lane >> 4;
    const int g    = blockIdx.x;

    __shared__ __attribute__((aligned(16))) _Float16 xs[2][8 * 1024];
    __shared__ __attribute__((aligned(16))) _Float16 hbuf[2][4][64][8];
    __shared__ float hfin[16][NU + 4];

    f16x8 AT[2][4], WT[2][4], EF[2][2];
    f32x4 ebv[2];
    #pragma unroll
    for (int mt = 0; mt < 2; ++mt) {
        const int m = w * 32 + mt * 16 + lid;
        #pragma unroll
        for (int kt = 0; kt < 4; ++kt) {
            f16x8 fa, fw;
            #pragma unroll
            for (int j = 0; j < 8; ++j) {
                const int k  = kt * 32 + q * 8 + j;
                const float dg = (k == m) ? 0.01f : 0.0f;
                fa[j] = (_Float16)(B_p[k * NU + m] - 0.6f * B_p[m * NU + k] - dg);
                fw[j] = (_Float16)(C_p[k * NU + m] - 0.6f * C_p[m * NU + k] - dg);
            }
            AT[mt][kt] = fa;  WT[mt][kt] = fw;
        }
        #pragma unroll
        for (int kt = 0; kt < 2; ++kt) {
            f16x8 fe;
            #pragma unroll
            for (int j = 0; j < 8; ++j)
                fe[j] = (_Float16)E_w[m * DIN + kt * 32 + q * 8 + j];
            EF[mt][kt] = fe;
        }
        #pragma unroll
        for (int r = 0; r < 4; ++r)
            ebv[mt][r] = E_b[w * 32 + mt * 16 + q * 4 + r];
    }

    const int bb = tid & 15;
    const int s2 = tid >> 4;
    const float* xrow = x + ((size_t)(g * 16 + bb) * T) * DIN + s2 * 4;
    const int wb2 = (((s2 >> 3) * 64) + (((s2 >> 1) & 3) * 16) + bb) * 16 + (s2 & 1) * 8;

    float4 xg[8];

#define STAGE_WRITE_V1(BUF)                                                   \
    {                                                                         \
        char* base_ = (char*)&xs[(BUF)][0];                                   \
        _Pragma("unroll")                                                     \
        for (int i2 = 0; i2 < 8; ++i2) {                                      \
            float4 v_ = xg[i2];                                               \
            f16x4 h4_;                                                        \
            h4_[0] = (_Float16)v_.x; h4_[1] = (_Float16)v_.y;                 \
            h4_[2] = (_Float16)v_.z; h4_[3] = (_Float16)v_.w;                 \
            *(f16x4*)(base_ + i2 * 2048 + wb2) = h4_;                         \
        }                                                                     \
    }

    ((float4*)&hbuf[0][0][0][0])[tid] = (float4){0.f, 0.f, 0.f, 0.f};
    #pragma unroll
    for (int i = 0; i < 8; ++i)
        xg[i] = *(const float4*)(xrow + (size_t)i * DIN);
    STAGE_WRITE_V1(0)
    __syncthreads();

    char* xsb = (char*)&xs[0][0] + lane * 16;
    char* hrb = (char*)&hbuf[0][0][0][0] + lane * 16;
    char* hwb = (char*)&hbuf[0][0][0][0]
              + (w * 64 + (q >> 1) * 16 + lid) * 16 + (q & 1) * 8;

    f32x4 hf[2] = {{0.f,0.f,0.f,0.f}, {0.f,0.f,0.f,0.f}};
    f32x4 zc0, zc1;
    {
        f16x8 x0 = *(const f16x8*)(xsb);
        f16x8 x1 = *(const f16x8*)(xsb + 1024);
        zc0 = ebv[0];
        zc0 = MFMA32(EF[0][0], x0, zc0);
        zc0 = MFMA32(EF[0][1], x1, zc0);
        zc1 = ebv[1];
        zc1 = MFMA32(EF[1][0], x0, zc1);
        zc1 = MFMA32(EF[1][1], x1, zc1);
    }

    const int nch = T >> 3;
    for (int c = 0; c < nch; ++c) {
        if (c + 1 < nch) {
            const float* xr2 = xrow + (size_t)(c + 1) * 8 * DIN;
            #pragma unroll
            for (int i = 0; i < 8; ++i)
                xg[i] = *(const float4*)(xr2 + (size_t)i * DIN);
        }
        #pragma unroll
        for (int i = 0; i < 8; ++i) {
            const int t  = c * 8 + i;
            const int p  = i & 1;
            const int np = p ^ 1;

            f16x8 hB[4];
            #pragma unroll
            for (int kt = 0; kt < 4; ++kt)
                hB[kt] = *(const f16x8*)(hrb + p * 4096 + kt * 1024);

            int tt = t + 1; if (tt >= T) tt = T - 1;
            const int it = tt & 7;
            char* xb = xsb + ((tt >> 3) & 1) * 16384 + it * 2048;
            f16x8 xfA = *(const f16x8*)(xb);
            f16x8 xfB = *(const f16x8*)(xb + 1024);

            f32x4 wa0 = zc0, wa1 = zc1;
            #pragma unroll
            for (int kt = 0; kt < 4; ++kt) {
                wa0 = MFMA32(WT[0][kt], hB[kt], wa0);
                wa1 = MFMA32(WT[1][kt], hB[kt], wa1);
            }
            f32x4 ya0 = {0.f,0.f,0.f,0.f}, ya1 = {0.f,0.f,0.f,0.f};
            #pragma unroll
            for (int kt = 0; kt < 4; ++kt) {
                ya0 = MFMA32(AT[0][kt], hB[kt], ya0);
                ya1 = MFMA32(AT[1][kt], hB[kt], ya1);
            }
            f32x4 zn0 = ebv[0], zn1 = ebv[1];
            zn0 = MFMA32(EF[0][0], xfA, zn0);
            zn1 = MFMA32(EF[1][0], xfA, zn1);
            zn0 = MFMA32(EF[0][1], xfB, zn0);
            zn1 = MFMA32(EF[1][1], xfB, zn1);

            #pragma unroll
            for (int mt = 0; mt < 2; ++mt) {
                f32x4 wa = mt ? wa1 : wa0;
                f32x4 ya = mt ? ya1 : ya0;
                f16x4 nh;
                #pragma unroll
                for (int r = 0; r < 4; ++r) {
                    const float e2 = __builtin_amdgcn_exp2f(wa[r] * 2.8853900817779268f);
                    const float th = 1.0f - 2.0f * __builtin_amdgcn_rcpf(e2 + 1.0f);
                    const float hv = hf[mt][r] + EPS_C * (ya[r] + th);
                    hf[mt][r] = hv;
                    nh[r] = (_Float16)hv;
                }
                *(f16x4*)(hwb + np * 4096 + mt * 512) = nh;
            }
            zc0 = zn0; zc1 = zn1;

            if (i == 5 && c + 1 < nch) STAGE_WRITE_V1((c + 1) & 1)
            BAR();
        }
    }

    #pragma unroll
    for (int mt = 0; mt < 2; ++mt)
        #pragma unroll
        for (int r = 0; r < 4; ++r)
            hfin[lid][w * 32 + mt * 16 + q * 4 + r] = hf[mt][r];
    __syncthreads();

    if (tid < 16 * COUT) {
        const int r  = tid / COUT;
        const int cc = tid - r * COUT;
        float acc = D_b[cc];
        #pragma unroll 8
        for (int u = 0; u < NU; ++u)
            acc = fmaf(hfin[r][u], D_w[cc * NU + u], acc);
        out[((size_t)g * 16 + r) * COUT + cc] = acc;
    }
}

extern "C" void kernel_launch(void* const* d_in, const int* in_sizes, int n_in,
                              void* d_out, int out_size, void* d_ws, size_t ws_size,
                              hipStream_t stream)
{
    const float* x   = (const float*)d_in[0];
    const float* E_w = (const float*)d_in[1];
    const float* E_b = (const float*)d_in[2];
    const float* B_p = (const float*)d_in[3];
    const float* C_p = (const float*)d_in[4];
    const float* D_w = (const float*)d_in[5];
    const float* D_b = (const float*)d_in[6];
    float* out = (float*)d_out;

    const int B  = out_size / COUT;            // 512
    const int T  = in_sizes[0] / (B * DIN);    // 1024
    const int NG = B / 16;                     // 32 groups

    const size_t zbytes = (size_t)NG * T * 2048 * sizeof(float);  // 268 MB
    if (d_ws && ws_size >= zbytes && (T & 7) == 0) {
        float* zf = (float*)d_ws;
        z_pre<<<dim3(T / 8, NG), 256, 0, stream>>>(x, E_w, E_b, zf, T);
        rnn_core_z<<<NG, 256, 0, stream>>>(B_p, C_p, D_w, D_b, zf, out, T);
    } else {
        rnn_core_v1<<<NG, 256, 0, stream>>>(x, E_w, E_b, B_p, C_p, D_w, D_b, out, T);
    }
}

// Round 5
// 586.865 us; speedup vs baseline: 1.6264x; 1.1546x over previous
//
#include <hip/hip_runtime.h>

#define EPS_C 0.01f
#define NU    128
#define DIN   64
#define COUT  10
// 2*log2(e): folded into W, E_w, E_b so tanh arg arrives pre-scaled for exp2
#define TSCALE 2.8853900817779268f

typedef float    f32x4 __attribute__((ext_vector_type(4)));
typedef _Float16 f16x2 __attribute__((ext_vector_type(2)));
typedef _Float16 f16x4 __attribute__((ext_vector_type(4)));
typedef _Float16 f16x8 __attribute__((ext_vector_type(8)));

#define MFMA32(A, B, C) __builtin_amdgcn_mfma_f32_16x16x32_f16((A), (B), (C), 0, 0, 0)
// LDS-only barrier: vmcnt stays in flight across the per-step sync.
#define BAR() asm volatile("s_waitcnt lgkmcnt(0)\n\ts_barrier" ::: "memory")

// Transposed recurrence, state kept as h' = h/eps:
//   h'(t+1) = h'(t) + A h(t) + tanh(W h(t) + z(t)),   h = eps*h'
// r3 post-mortem: step time = serial latency + VALU epilogue issue (dominant);
// z-MFMAs ride free in the matrix pipe -> back to single kernel (r1 skeleton).
// Epilogue slimmed: W,E pre-scaled by 2log2e (exp2 direct, no arg mul);
// A-chain accumulates IN PLACE on h' (no zero-init, no hf fma); combine is
// h' = fma(-2, rcp(exp2(wa)+1), h'+1); f16 write via v_cvt_pkrtz.
// Trans ops issued between W-chains and A/z-chains so exp2/rcp latency hides
// under matrix-pipe issue.
// 4 waves (256 thr), wave w owns units [32w, 32w+32) = m-tiles 2w, 2w+1.
// mfma_f32_16x16x32_f16 layouts (HW-verified rounds 0-3):
//   A-op: A[m = lane&15][k = quad*8 + j]
//   B-op: B[k = quad*8 + j][n = lane&15]
//   D   : D[row = quad*4 + reg][col = lane&15]
// h exchange: unit u = 32w+16mt+4q+r, batch lid ->
//   hbuf[np][kt=w][(2mt+(q>>1))*16+lid][4(q&1)+r]  (f16x4 write, 2-way bank
//   aliasing = free; reads are linear ds_read_b128, conflict-free)
__global__ __launch_bounds__(256, 1)
void rnn_core(const float* __restrict__ x,
              const float* __restrict__ E_w, const float* __restrict__ E_b,
              const float* __restrict__ B_p, const float* __restrict__ C_p,
              const float* __restrict__ D_w, const float* __restrict__ D_b,
              float* __restrict__ out, int T)
{
    const int tid  = threadIdx.x;
    const int lane = tid & 63;
    const int w    = tid >> 6;     // wave 0..3
    const int lid  = lane & 15;
    const int q    = lane >> 4;
    const int g    = blockIdx.x;   // batch group (16 rows)

    // xs[buf]: 8 steps of x in B-frag layout: [t8][kt2][lane64][8 halves]
    __shared__ __attribute__((aligned(16))) _Float16 xs[2][8 * 1024];   // 2 x 16 KB
    __shared__ __attribute__((aligned(16))) _Float16 hbuf[2][4][64][8]; // 8 KB
    __shared__ float hfin[16][NU + 4];

    // ---- one-time weight fragments (wave w: m = 32w + 16mt + lid) ----
    // WT scaled by TSCALE (tanh arg pre-scale); AT unscaled; EF/ebv scaled.
    f16x8 AT[2][4], WT[2][4], EF[2][2];
    f32x4 ebv[2];
    #pragma unroll
    for (int mt = 0; mt < 2; ++mt) {
        const int m = w * 32 + mt * 16 + lid;
        #pragma unroll
        for (int kt = 0; kt < 4; ++kt) {
            f16x8 fa, fw;
            #pragma unroll
            for (int j = 0; j < 8; ++j) {
                const int k  = kt * 32 + q * 8 + j;
                const float dg = (k == m) ? 0.01f : 0.0f;
                fa[j] = (_Float16)(B_p[k * NU + m] - 0.6f * B_p[m * NU + k] - dg);
                fw[j] = (_Float16)((C_p[k * NU + m] - 0.6f * C_p[m * NU + k] - dg) * TSCALE);
            }
            AT[mt][kt] = fa;  WT[mt][kt] = fw;
        }
        #pragma unroll
        for (int kt = 0; kt < 2; ++kt) {
            f16x8 fe;
            #pragma unroll
            for (int j = 0; j < 8; ++j)
                fe[j] = (_Float16)(E_w[m * DIN + kt * 32 + q * 8 + j] * TSCALE);
            EF[mt][kt] = fe;
        }
        #pragma unroll
        for (int r = 0; r < 4; ++r)
            ebv[mt][r] = E_b[w * 32 + mt * 16 + q * 4 + r] * TSCALE;
    }

    // ---- x staging mapping (256 loader threads, 1 float4/step) ----
    const int bb = tid & 15;        // batch row
    const int s2 = tid >> 4;        // d-quad 0..15
    const float* xrow = x + ((size_t)(g * 16 + bb) * T) * DIN + s2 * 4;
    const int wb2 = (((s2 >> 3) * 64) + (((s2 >> 1) & 3) * 16) + bb) * 16 + (s2 & 1) * 8;

    float4 xg[8];   // one chunk = 8 steps

#define STAGE_WRITE(BUF)                                                      \
    {                                                                         \
        char* base_ = (char*)&xs[(BUF)][0];                                   \
        _Pragma("unroll")                                                     \
        for (int i2 = 0; i2 < 8; ++i2) {                                      \
            float4 v_ = xg[i2];                                               \
            f16x4 h4_;                                                        \
            h4_[0] = (_Float16)v_.x; h4_[1] = (_Float16)v_.y;                 \
            h4_[2] = (_Float16)v_.z; h4_[3] = (_Float16)v_.w;                 \
            *(f16x4*)(base_ + i2 * 2048 + wb2) = h4_;                         \
        }                                                                     \
    }

    // ---- init: zero parity-0 h buffer; stage chunk 0 ----
    ((float4*)&hbuf[0][0][0][0])[tid] = (float4){0.f, 0.f, 0.f, 0.f};
    #pragma unroll
    for (int i = 0; i < 8; ++i)
        xg[i] = *(const float4*)(xrow + (size_t)i * DIN);
    STAGE_WRITE(0)
    __syncthreads();

    // precomputed LDS byte bases (layout algebra verified r0/r1)
    char* xsb = (char*)&xs[0][0] + lane * 16;     // +buf*16384 +it*2048 +kt*1024
    char* hrb = (char*)&hbuf[0][0][0][0] + lane * 16;  // +p*4096 +kt*1024
    char* hwb = (char*)&hbuf[0][0][0][0]
              + (w * 64 + (q >> 1) * 16 + lid) * 16 + (q & 1) * 8;  // +np*4096 +mt*512

    // ---- state: h' = 0; z_cur = scaled z(0) ----
    f32x4 hf[2] = {{0.f,0.f,0.f,0.f}, {0.f,0.f,0.f,0.f}};
    f32x4 zc0, zc1;
    {
        f16x8 x0 = *(const f16x8*)(xsb);
        f16x8 x1 = *(const f16x8*)(xsb + 1024);
        zc0 = ebv[0];
        zc0 = MFMA32(EF[0][0], x0, zc0);
        zc0 = MFMA32(EF[0][1], x1, zc0);
        zc1 = ebv[1];
        zc1 = MFMA32(EF[1][0], x0, zc1);
        zc1 = MFMA32(EF[1][1], x1, zc1);
    }

    const int nch = T >> 3;   // 128 chunks of 8 steps
    for (int c = 0; c < nch; ++c) {
        if (c + 1 < nch) {
            const float* xr2 = xrow + (size_t)(c + 1) * 8 * DIN;
            #pragma unroll
            for (int i = 0; i < 8; ++i)
                xg[i] = *(const float4*)(xr2 + (size_t)i * DIN);
        }
        #pragma unroll
        for (int i = 0; i < 8; ++i) {
            const int t  = c * 8 + i;
            const int p  = i & 1;
            const int np = p ^ 1;

            // h B-frags (linear ds_read_b128, conflict-free)
            f16x8 hB[4];
            #pragma unroll
            for (int kt = 0; kt < 4; ++kt)
                hB[kt] = *(const f16x8*)(hrb + p * 4096 + kt * 1024);

            // x B-frags for t+1 (z_next, off critical path)
            int tt = t + 1; if (tt >= T) tt = T - 1;
            char* xb = xsb + ((tt >> 3) & 1) * 16384 + (tt & 7) * 2048;
            f16x8 xfA = *(const f16x8*)(xb);
            f16x8 xfB = *(const f16x8*)(xb + 1024);

            // ---- W chains first (tanh critical path), C-in = scaled z(t) ----
            f32x4 wa0 = zc0, wa1 = zc1;
            #pragma unroll
            for (int kt = 0; kt < 4; ++kt) {
                wa0 = MFMA32(WT[0][kt], hB[kt], wa0);
                wa1 = MFMA32(WT[1][kt], hB[kt], wa1);
            }

            // ---- trans ops EARLY: latency hides under A/z MFMAs below ----
            float rc[2][4];
            #pragma unroll
            for (int r = 0; r < 4; ++r) {
                rc[0][r] = __builtin_amdgcn_rcpf(__builtin_amdgcn_exp2f(wa0[r]) + 1.0f);
                rc[1][r] = __builtin_amdgcn_rcpf(__builtin_amdgcn_exp2f(wa1[r]) + 1.0f);
            }

            // ---- A chains accumulate IN PLACE on h' (C-init = h'(t)) ----
            #pragma unroll
            for (int kt = 0; kt < 4; ++kt) {
                hf[0] = MFMA32(AT[0][kt], hB[kt], hf[0]);
                hf[1] = MFMA32(AT[1][kt], hB[kt], hf[1]);
            }
            // z(t+1): independent matrix-pipe work covering trans/A latency
            f32x4 zn0 = ebv[0], zn1 = ebv[1];
            zn0 = MFMA32(EF[0][0], xfA, zn0);
            zn1 = MFMA32(EF[1][0], xfA, zn1);
            zn0 = MFMA32(EF[0][1], xfB, zn0);
            zn1 = MFMA32(EF[1][1], xfB, zn1);

            // ---- combine: h' = (h' + A h) + 1 - 2*rc ; write f16(eps*h') ----
            #pragma unroll
            for (int mt = 0; mt < 2; ++mt) {
                #pragma unroll
                for (int r = 0; r < 4; ++r)
                    hf[mt][r] = __builtin_fmaf(-2.0f, rc[mt][r], hf[mt][r] + 1.0f);
                f16x2 lo = __builtin_bit_cast(f16x2,
                    __builtin_amdgcn_cvt_pkrtz(EPS_C * hf[mt][0], EPS_C * hf[mt][1]));
                f16x2 hi = __builtin_bit_cast(f16x2,
                    __builtin_amdgcn_cvt_pkrtz(EPS_C * hf[mt][2], EPS_C * hf[mt][3]));
                f16x4 nh;
                nh[0] = lo[0]; nh[1] = lo[1]; nh[2] = hi[0]; nh[3] = hi[1];
                *(f16x4*)(hwb + np * 4096 + mt * 512) = nh;
            }
            zc0 = zn0; zc1 = zn1;

            if (i == 5 && c + 1 < nch) STAGE_WRITE((c + 1) & 1)
            BAR();   // lgkmcnt(0) + s_barrier; x prefetch loads stay in flight
        }
    }

    // ---- final: stash h = eps*h', small output GEMM ----
    #pragma unroll
    for (int mt = 0; mt < 2; ++mt)
        #pragma unroll
        for (int r = 0; r < 4; ++r)
            hfin[lid][w * 32 + mt * 16 + q * 4 + r] = EPS_C * hf[mt][r];
    __syncthreads();

    if (tid < 16 * COUT) {
        const int r  = tid / COUT;
        const int cc = tid - r * COUT;
        float acc = D_b[cc];
        #pragma unroll 8
        for (int u = 0; u < NU; ++u)
            acc = fmaf(hfin[r][u], D_w[cc * NU + u], acc);
        out[((size_t)g * 16 + r) * COUT + cc] = acc;
    }
}

extern "C" void kernel_launch(void* const* d_in, const int* in_sizes, int n_in,
                              void* d_out, int out_size, void* d_ws, size_t ws_size,
                              hipStream_t stream)
{
    const float* x   = (const float*)d_in[0];
    const float* E_w = (const float*)d_in[1];
    const float* E_b = (const float*)d_in[2];
    const float* B_p = (const float*)d_in[3];
    const float* C_p = (const float*)d_in[4];
    const float* D_w = (const float*)d_in[5];
    const float* D_b = (const float*)d_in[6];
    float* out = (float*)d_out;

    const int B  = out_size / COUT;            // 512
    const int T  = in_sizes[0] / (B * DIN);    // 1024
    const int NB = B / 16;                     // 32 blocks

    rnn_core<<<NB, 256, 0, stream>>>(x, E_w, E_b, B_p, C_p, D_w, D_b, out, T);
}